// Round 11
// baseline (1771.872 us; speedup 1.0000x reference)
//
#include <hip/hip_runtime.h>
#include <hip/hip_bf16.h>
#include <hip/hip_fp16.h>

#define FDIM 128

typedef float f4 __attribute__((ext_vector_type(4)));

// ---------- degree / dinv : XCD-filtered ----------
// Octant-group (bid&7 -> XCD) streams ALL of col with NT loads (sequential,
// fully-utilized, zero-reuse: the safe nt case) so the stream cannot evict
// the octant's L2-resident 50KB deg slice; atomics stay L2-local.

__global__ __launch_bounds__(256) void degree_oct_kernel(
        const int* __restrict__ col, int* __restrict__ deg, int N, int E, int M) {
    int o = blockIdx.x & 7;
    int j = blockIdx.x >> 3;
    int lo = (int)(((long)o * N) >> 3);
    int hi = (int)(((long)(o + 1) * N) >> 3);
    for (int e = j * 256 + threadIdx.x; e < E; e += M * 256) {
        int c = __builtin_nontemporal_load(col + e);
        if (c >= lo && c < hi) atomicAdd(&deg[c], 1);
    }
}

__global__ void dinv_kernel(const int* __restrict__ deg, float* __restrict__ dinv, int N) {
    int i = blockIdx.x * blockDim.x + threadIdx.x;
    if (i < N) {
        int d = deg[i];
        dinv[i] = (d > 0) ? rsqrtf((float)d) : 0.0f;
    }
}

// ---------- exclusive scan of deg -> rowptr ----------

__global__ void scan_blocks_kernel(const int* __restrict__ deg, int* __restrict__ rowptr,
                                   int* __restrict__ bsum, int N) {
    __shared__ int s[256];
    int t = threadIdx.x;
    int i = blockIdx.x * 256 + t;
    int v = (i < N) ? deg[i] : 0;
    s[t] = v;
    __syncthreads();
    for (int off = 1; off < 256; off <<= 1) {
        int add = (t >= off) ? s[t - off] : 0;
        __syncthreads();
        s[t] += add;
        __syncthreads();
    }
    if (i < N) rowptr[i] = s[t] - v;
    if (t == 255) bsum[blockIdx.x] = s[255];
}

__global__ void scan_bsums_kernel(int* __restrict__ bsum, int* __restrict__ boff, int nb) {
    __shared__ int s[512];
    int t = threadIdx.x;
    int v = (t < nb) ? bsum[t] : 0;
    s[t] = v;
    __syncthreads();
    for (int off = 1; off < 512; off <<= 1) {
        int add = (t >= off) ? s[t - off] : 0;
        __syncthreads();
        s[t] += add;
        __syncthreads();
    }
    if (t < nb) boff[t] = s[t] - v;
}

__global__ void add_offsets_kernel(int* __restrict__ rowptr, int* __restrict__ cursor,
                                   const int* __restrict__ boff, int N, int E) {
    int i = blockIdx.x * blockDim.x + threadIdx.x;
    if (i < N) {
        int v = rowptr[i] + boff[i >> 8];
        rowptr[i] = v;
        cursor[i] = v;
    }
    if (i == 0) rowptr[N] = E;
}

// ---------- edge placement: XCD-filtered replicated-read scatter ----------
// r10 post-mortem: octant slices fit L2 but the CACHEABLE col/row stream
// (205MB through each XCD) was evicting the dirty eidx lines -> WRITE stayed
// 172MB. NT the stream reads (sequential fully-utilized lines, r3-safe) so
// only cursor (50KB) + eidx slice (1.6MB) occupy L2; dirty lines then
// accumulate all ~16 sharers before writeback.

__global__ __launch_bounds__(256) void place_oct_kernel(
        const int* __restrict__ row, const int* __restrict__ col,
        int* __restrict__ cursor, int* __restrict__ eidx, int N, int E, int M) {
    int o = blockIdx.x & 7;
    int j = blockIdx.x >> 3;
    int lo = (int)(((long)o * N) >> 3);
    int hi = (int)(((long)(o + 1) * N) >> 3);
    for (int e = j * 256 + threadIdx.x; e < E; e += M * 256) {
        int c = __builtin_nontemporal_load(col + e);
        int r = __builtin_nontemporal_load(row + e);
        if (c >= lo && c < hi) {
            int pos = atomicAdd(&cursor[c], 1);
            eidx[pos] = r;
        }
    }
}

// ---------- out = mf[0] * x ; hx = fp16(dinv[n] * x), flat layout ----------

__global__ void init_out_kernel(const float4* __restrict__ x, const float* __restrict__ mf,
                                const float* __restrict__ dinv,
                                float4* __restrict__ out, float4* __restrict__ hx, long n8) {
    long i = (long)blockIdx.x * blockDim.x + threadIdx.x;
    if (i < n8) {
        float w = mf[0];
        float4 a = x[2 * i];
        float4 b = x[2 * i + 1];
        out[2 * i]     = make_float4(w * a.x, w * a.y, w * a.z, w * a.w);
        out[2 * i + 1] = make_float4(w * b.x, w * b.y, w * b.z, w * b.w);
        float dv = dinv[i >> 4];     // node = i/16 (16 threads per 128-f row)
        __half2 h[4];
        h[0] = __floats2half2_rn(dv * a.x, dv * a.y);
        h[1] = __floats2half2_rn(dv * a.z, dv * a.w);
        h[2] = __floats2half2_rn(dv * b.x, dv * b.y);
        h[3] = __floats2half2_rn(dv * b.z, dv * b.w);
        hx[i] = *(const float4*)h;
    }
}

// ---------- fused gather prop, 4 edges per wave (r2-proven shape) ----------
// At the gather structural floor (~140us: 800K 1KB-gathers, ~4.4M compulsory
// per-XCD fills; r2->r10 traffic 947->527MB moved time only 150->142us) —
// do not touch the loop. Shadow carries dinv[r] (r3 math):
//   P_i(d) = scale * dinv[d] * sum_e shadow_{i-1}[r_e] + beta * P_{i-2}(d)
//   shadow_i(d) = fp16(dinv[d] * P_i(d)) ; out += coef * P_i(d)
// Last pass: tgt==nullptr (P_K never read; skip 51MB store).

__global__ __launch_bounds__(256) void gather_prop_kernel(
        const int* __restrict__ eidx, const int* __restrict__ rowptr,
        const float* __restrict__ dinv,
        const __half* __restrict__ src, const float* __restrict__ prev2,
        float* __restrict__ tgt, __half* __restrict__ tgth, float* __restrict__ out,
        const float* __restrict__ mf, const float* __restrict__ lap,
        int i_coef, float scale, float beta, int N) {
    int wid = blockIdx.x * 4 + (threadIdx.x >> 6);
    if (wid >= N) return;
    int lane = threadIdx.x & 63;
    int g  = lane >> 4;        // edge group within wave
    int fl = lane & 15;        // feature lane
    int feoff = fl << 3;       // element offset within a 128-elem row

    int begin = rowptr[wid];
    int end   = rowptr[wid + 1];

    float acc[8];
    #pragma unroll
    for (int j = 0; j < 8; ++j) acc[j] = 0.f;

    #pragma unroll 4
    for (int e0 = begin; e0 < end; e0 += 4) {
        int e = e0 + g;
        float wsel = 0.f;
        int idx = 0;
        if (e < end) {
            idx = eidx[e];
            wsel = 1.f;
        }
        f4 raw = *(const f4*)(src + ((long)idx << 7) + feoff);
        const __half2* h = (const __half2*)&raw;
        float2 f0 = __half22float2(h[0]);
        float2 f1 = __half22float2(h[1]);
        float2 f2 = __half22float2(h[2]);
        float2 f3 = __half22float2(h[3]);
        acc[0] += wsel * f0.x; acc[1] += wsel * f0.y;
        acc[2] += wsel * f1.x; acc[3] += wsel * f1.y;
        acc[4] += wsel * f2.x; acc[5] += wsel * f2.y;
        acc[6] += wsel * f3.x; acc[7] += wsel * f3.y;
    }

    // reduce the 4 edge groups (lanes fl, fl+16, fl+32, fl+48)
    #pragma unroll
    for (int j = 0; j < 8; ++j) {
        acc[j] += __shfl_xor(acc[j], 16, 64);
        acc[j] += __shfl_xor(acc[j], 32, 64);
    }

    if (g == 0) {
        float dv   = dinv[wid];
        float sdv  = scale * dv;
        float coef = mf[i_coef] * lap[i_coef - 1];
        long o = ((long)wid << 7) + feoff;   // element offset
        float r[8];
        if (beta != 0.f) {
            f4 p0 = __builtin_nontemporal_load((const f4*)(prev2 + o));
            f4 p1 = __builtin_nontemporal_load((const f4*)(prev2 + o) + 1);
            r[0] = sdv * acc[0] + beta * p0.x;
            r[1] = sdv * acc[1] + beta * p0.y;
            r[2] = sdv * acc[2] + beta * p0.z;
            r[3] = sdv * acc[3] + beta * p0.w;
            r[4] = sdv * acc[4] + beta * p1.x;
            r[5] = sdv * acc[5] + beta * p1.y;
            r[6] = sdv * acc[6] + beta * p1.z;
            r[7] = sdv * acc[7] + beta * p1.w;
        } else {
            #pragma unroll
            for (int j = 0; j < 8; ++j) r[j] = sdv * acc[j];
        }
        if (tgt) {
            f4 t0 = {r[0], r[1], r[2], r[3]};
            f4 t1 = {r[4], r[5], r[6], r[7]};
            __builtin_nontemporal_store(t0, (f4*)(tgt + o));
            __builtin_nontemporal_store(t1, (f4*)(tgt + o) + 1);
        }
        if (tgth) {
            __half2 hh[4];
            hh[0] = __floats2half2_rn(dv * r[0], dv * r[1]);
            hh[1] = __floats2half2_rn(dv * r[2], dv * r[3]);
            hh[2] = __floats2half2_rn(dv * r[4], dv * r[5]);
            hh[3] = __floats2half2_rn(dv * r[6], dv * r[7]);
            __builtin_nontemporal_store(*(const f4*)hh, (f4*)(tgth + o));
        }
        f4 o0 = __builtin_nontemporal_load((const f4*)(out + o));
        f4 o1 = __builtin_nontemporal_load((const f4*)(out + o) + 1);
        o0.x += coef * r[0]; o0.y += coef * r[1]; o0.z += coef * r[2]; o0.w += coef * r[3];
        o1.x += coef * r[4]; o1.y += coef * r[5]; o1.z += coef * r[6]; o1.w += coef * r[7];
        __builtin_nontemporal_store(o0, (f4*)(out + o));
        __builtin_nontemporal_store(o1, (f4*)(out + o) + 1);
    }
}

extern "C" void kernel_launch(void* const* d_in, const int* in_sizes, int n_in,
                              void* d_out, int out_size, void* d_ws, size_t ws_size,
                              hipStream_t stream) {
    const float* x   = (const float*)d_in[0];
    const float* mf  = (const float*)d_in[1];
    const float* lap = (const float*)d_in[2];
    const int*   ei  = (const int*)d_in[3];
    float* out = (float*)d_out;

    const int  K  = in_sizes[1] - 1;          // 10
    const long NF = (long)in_sizes[0];        // N*F
    const int  N  = (int)(NF / FDIM);         // 100000
    const int  E  = in_sizes[3] / 2;          // 3200000
    const int* row = ei;
    const int* col = ei + E;

    // workspace layout (~170 MB)
    char* wp = (char*)d_ws;
    float*  bufA   = (float*)wp;  wp += NF * sizeof(float);
    float*  bufB   = (float*)wp;  wp += NF * sizeof(float);
    __half* hbufA  = (__half*)wp; wp += NF * sizeof(__half);
    __half* hbufB  = (__half*)wp; wp += NF * sizeof(__half);
    int*    eidx   = (int*)wp;    wp += (size_t)E * sizeof(int);
    int*    rowptr = (int*)wp;    wp += (size_t)(N + 1) * sizeof(int);
    int*    cursor = (int*)wp;    wp += (size_t)N * sizeof(int);
    int*    deg    = (int*)wp;    wp += (size_t)N * sizeof(int);
    float*  dinv   = (float*)wp;  wp += (size_t)N * sizeof(float);
    int*    bsum   = (int*)wp;    wp += 512 * sizeof(int);
    int*    boff   = (int*)wp;    wp += 512 * sizeof(int);

    const int BT = 256;
    const long n8 = NF / 8;
    const int n8_blocks = (int)((n8 + BT - 1) / BT);
    const int n_blocks  = (N + BT - 1) / BT;
    const int M = 192;   // blocks per octant for filtered kernels

    // CSR build
    hipMemsetAsync(deg, 0, (size_t)N * sizeof(int), stream);
    degree_oct_kernel<<<8 * M, BT, 0, stream>>>(col, deg, N, E, M);
    dinv_kernel<<<n_blocks, BT, 0, stream>>>(deg, dinv, N);
    scan_blocks_kernel<<<n_blocks, BT, 0, stream>>>(deg, rowptr, bsum, N);
    scan_bsums_kernel<<<1, 512, 0, stream>>>(bsum, boff, n_blocks);
    add_offsets_kernel<<<n_blocks, BT, 0, stream>>>(rowptr, cursor, boff, N, E);
    place_oct_kernel<<<8 * M, BT, 0, stream>>>(row, col, cursor, eidx, N, E, M);

    // out = mf0 * x ; hbufB = fp16(dinv*x) flat  (hbufB free until i=2 writes it)
    init_out_kernel<<<n8_blocks, BT, 0, stream>>>((const float4*)x, mf, dinv,
                                                  (float4*)out, (float4*)hbufB, n8);

    const int g_blocks = (N + 3) / 4;

    // P1 = prop(x) -> bufA (+hbufA) ; out += c1*P1   (gathers fp16 dinv*x)
    gather_prop_kernel<<<g_blocks, BT, 0, stream>>>(eidx, rowptr, dinv, hbufB, x,
                                                    bufA, hbufA, out, mf, lap,
                                                    1, 1.0f, 0.0f, N);
    // P_i = 2*prop(P_{i-1}) - P_{i-2} ; out += c_i*P_i   (gathers fp16 shadow)
    for (int i = 2; i <= K; ++i) {
        const __half* srch  = (i % 2 == 0) ? hbufA : hbufB;  // fp16(dinv*P_{i-1})
        float*        tgt   = (i % 2 == 0) ? bufB : bufA;    // P_i (overwrites P_{i-2})
        __half*       tgth  = (i % 2 == 0) ? hbufB : hbufA;
        const float*  prev2 = (i == 2) ? x : (const float*)tgt;
        if (i == K) { tgth = nullptr; tgt = nullptr; }  // P_K, shadow_K never read
        gather_prop_kernel<<<g_blocks, BT, 0, stream>>>(eidx, rowptr, dinv, srch, prev2,
                                                        tgt, tgth, out, mf, lap,
                                                        i, 2.0f, -1.0f, N);
    }
}

// Round 12
// 1755.168 us; speedup vs baseline: 1.0095x; 1.0095x over previous
//
#include <hip/hip_runtime.h>
#include <hip/hip_bf16.h>
#include <hip/hip_fp16.h>

#define FDIM 128

typedef float f4 __attribute__((ext_vector_type(4)));

// ---------- degree / dinv : XCD-filtered ----------
// Octant-group (bid&7 -> XCD) streams ALL of col (cacheable: L3 serves the
// 8x-replicated 12.8MB stream; r11 showed nt reads here cost +5us by pushing
// the stream to HBM latency) and atomics only its own 50KB deg slice.

__global__ __launch_bounds__(256) void degree_oct_kernel(
        const int* __restrict__ col, int* __restrict__ deg, int N, int E, int M) {
    int o = blockIdx.x & 7;
    int j = blockIdx.x >> 3;
    int lo = (int)(((long)o * N) >> 3);
    int hi = (int)(((long)(o + 1) * N) >> 3);
    for (int e = j * 256 + threadIdx.x; e < E; e += M * 256) {
        int c = col[e];
        if (c >= lo && c < hi) atomicAdd(&deg[c], 1);
    }
}

__global__ void dinv_kernel(const int* __restrict__ deg, float* __restrict__ dinv, int N) {
    int i = blockIdx.x * blockDim.x + threadIdx.x;
    if (i < N) {
        int d = deg[i];
        dinv[i] = (d > 0) ? rsqrtf((float)d) : 0.0f;
    }
}

// ---------- exclusive scan of deg -> rowptr ----------

__global__ void scan_blocks_kernel(const int* __restrict__ deg, int* __restrict__ rowptr,
                                   int* __restrict__ bsum, int N) {
    __shared__ int s[256];
    int t = threadIdx.x;
    int i = blockIdx.x * 256 + t;
    int v = (i < N) ? deg[i] : 0;
    s[t] = v;
    __syncthreads();
    for (int off = 1; off < 256; off <<= 1) {
        int add = (t >= off) ? s[t - off] : 0;
        __syncthreads();
        s[t] += add;
        __syncthreads();
    }
    if (i < N) rowptr[i] = s[t] - v;
    if (t == 255) bsum[blockIdx.x] = s[255];
}

__global__ void scan_bsums_kernel(int* __restrict__ bsum, int* __restrict__ boff, int nb) {
    __shared__ int s[512];
    int t = threadIdx.x;
    int v = (t < nb) ? bsum[t] : 0;
    s[t] = v;
    __syncthreads();
    for (int off = 1; off < 512; off <<= 1) {
        int add = (t >= off) ? s[t - off] : 0;
        __syncthreads();
        s[t] += add;
        __syncthreads();
    }
    if (t < nb) boff[t] = s[t] - v;
}

__global__ void add_offsets_kernel(int* __restrict__ rowptr, int* __restrict__ cursor,
                                   const int* __restrict__ boff, int N, int E) {
    int i = blockIdx.x * blockDim.x + threadIdx.x;
    if (i < N) {
        int v = rowptr[i] + boff[i >> 8];
        rowptr[i] = v;
        cursor[i] = v;
    }
    if (i == 0) rowptr[N] = E;
}

// ---------- edge placement: XCD-filtered replicated-read scatter ----------
// r10 configuration (best measured: 142us). Octant-group o places only edges
// with dst in its slice -> cursor (50KB) + eidx slice (1.6MB) are L2-local.
// col/row reads stay CACHEABLE (L3-served; r11's nt variant was slower).

__global__ __launch_bounds__(256) void place_oct_kernel(
        const int* __restrict__ row, const int* __restrict__ col,
        int* __restrict__ cursor, int* __restrict__ eidx, int N, int E, int M) {
    int o = blockIdx.x & 7;
    int j = blockIdx.x >> 3;
    int lo = (int)(((long)o * N) >> 3);
    int hi = (int)(((long)(o + 1) * N) >> 3);
    for (int e = j * 256 + threadIdx.x; e < E; e += M * 256) {
        int c = col[e];
        if (c >= lo && c < hi) {
            int pos = atomicAdd(&cursor[c], 1);
            eidx[pos] = row[e];
        }
    }
}

// ---------- out = mf[0] * x ; hx = fp16(dinv[n] * x), flat layout ----------

__global__ void init_out_kernel(const float4* __restrict__ x, const float* __restrict__ mf,
                                const float* __restrict__ dinv,
                                float4* __restrict__ out, float4* __restrict__ hx, long n8) {
    long i = (long)blockIdx.x * blockDim.x + threadIdx.x;
    if (i < n8) {
        float w = mf[0];
        float4 a = x[2 * i];
        float4 b = x[2 * i + 1];
        out[2 * i]     = make_float4(w * a.x, w * a.y, w * a.z, w * a.w);
        out[2 * i + 1] = make_float4(w * b.x, w * b.y, w * b.z, w * b.w);
        float dv = dinv[i >> 4];     // node = i/16 (16 threads per 128-f row)
        __half2 h[4];
        h[0] = __floats2half2_rn(dv * a.x, dv * a.y);
        h[1] = __floats2half2_rn(dv * a.z, dv * a.w);
        h[2] = __floats2half2_rn(dv * b.x, dv * b.y);
        h[3] = __floats2half2_rn(dv * b.z, dv * b.w);
        hx[i] = *(const float4*)h;
    }
}

// ---------- fused gather prop, 4 edges per wave (r2-proven shape) ----------
// At the gather structural floor (~140us: 800K 1KB-gathers; falsified levers:
// byte cut 947->527MB null, unroll 4->8 null, L2-chunking slower). Shadow
// carries dinv[r] (r3 math):
//   P_i(d) = scale * dinv[d] * sum_e shadow_{i-1}[r_e] + beta * P_{i-2}(d)
//   shadow_i(d) = fp16(dinv[d] * P_i(d)) ; out += coef * P_i(d)
// Last pass: tgt=tgth=nullptr (P_K / shadow_K never read; skip 77MB stores).

__global__ __launch_bounds__(256) void gather_prop_kernel(
        const int* __restrict__ eidx, const int* __restrict__ rowptr,
        const float* __restrict__ dinv,
        const __half* __restrict__ src, const float* __restrict__ prev2,
        float* __restrict__ tgt, __half* __restrict__ tgth, float* __restrict__ out,
        const float* __restrict__ mf, const float* __restrict__ lap,
        int i_coef, float scale, float beta, int N) {
    int wid = blockIdx.x * 4 + (threadIdx.x >> 6);
    if (wid >= N) return;
    int lane = threadIdx.x & 63;
    int g  = lane >> 4;        // edge group within wave
    int fl = lane & 15;        // feature lane
    int feoff = fl << 3;       // element offset within a 128-elem row

    int begin = rowptr[wid];
    int end   = rowptr[wid + 1];

    float acc[8];
    #pragma unroll
    for (int j = 0; j < 8; ++j) acc[j] = 0.f;

    #pragma unroll 4
    for (int e0 = begin; e0 < end; e0 += 4) {
        int e = e0 + g;
        float wsel = 0.f;
        int idx = 0;
        if (e < end) {
            idx = eidx[e];
            wsel = 1.f;
        }
        f4 raw = *(const f4*)(src + ((long)idx << 7) + feoff);
        const __half2* h = (const __half2*)&raw;
        float2 f0 = __half22float2(h[0]);
        float2 f1 = __half22float2(h[1]);
        float2 f2 = __half22float2(h[2]);
        float2 f3 = __half22float2(h[3]);
        acc[0] += wsel * f0.x; acc[1] += wsel * f0.y;
        acc[2] += wsel * f1.x; acc[3] += wsel * f1.y;
        acc[4] += wsel * f2.x; acc[5] += wsel * f2.y;
        acc[6] += wsel * f3.x; acc[7] += wsel * f3.y;
    }

    // reduce the 4 edge groups (lanes fl, fl+16, fl+32, fl+48)
    #pragma unroll
    for (int j = 0; j < 8; ++j) {
        acc[j] += __shfl_xor(acc[j], 16, 64);
        acc[j] += __shfl_xor(acc[j], 32, 64);
    }

    if (g == 0) {
        float dv   = dinv[wid];
        float sdv  = scale * dv;
        float coef = mf[i_coef] * lap[i_coef - 1];
        long o = ((long)wid << 7) + feoff;   // element offset
        float r[8];
        if (beta != 0.f) {
            f4 p0 = __builtin_nontemporal_load((const f4*)(prev2 + o));
            f4 p1 = __builtin_nontemporal_load((const f4*)(prev2 + o) + 1);
            r[0] = sdv * acc[0] + beta * p0.x;
            r[1] = sdv * acc[1] + beta * p0.y;
            r[2] = sdv * acc[2] + beta * p0.z;
            r[3] = sdv * acc[3] + beta * p0.w;
            r[4] = sdv * acc[4] + beta * p1.x;
            r[5] = sdv * acc[5] + beta * p1.y;
            r[6] = sdv * acc[6] + beta * p1.z;
            r[7] = sdv * acc[7] + beta * p1.w;
        } else {
            #pragma unroll
            for (int j = 0; j < 8; ++j) r[j] = sdv * acc[j];
        }
        if (tgt) {
            f4 t0 = {r[0], r[1], r[2], r[3]};
            f4 t1 = {r[4], r[5], r[6], r[7]};
            __builtin_nontemporal_store(t0, (f4*)(tgt + o));
            __builtin_nontemporal_store(t1, (f4*)(tgt + o) + 1);
        }
        if (tgth) {
            __half2 hh[4];
            hh[0] = __floats2half2_rn(dv * r[0], dv * r[1]);
            hh[1] = __floats2half2_rn(dv * r[2], dv * r[3]);
            hh[2] = __floats2half2_rn(dv * r[4], dv * r[5]);
            hh[3] = __floats2half2_rn(dv * r[6], dv * r[7]);
            __builtin_nontemporal_store(*(const f4*)hh, (f4*)(tgth + o));
        }
        f4 o0 = __builtin_nontemporal_load((const f4*)(out + o));
        f4 o1 = __builtin_nontemporal_load((const f4*)(out + o) + 1);
        o0.x += coef * r[0]; o0.y += coef * r[1]; o0.z += coef * r[2]; o0.w += coef * r[3];
        o1.x += coef * r[4]; o1.y += coef * r[5]; o1.z += coef * r[6]; o1.w += coef * r[7];
        __builtin_nontemporal_store(o0, (f4*)(out + o));
        __builtin_nontemporal_store(o1, (f4*)(out + o) + 1);
    }
}

extern "C" void kernel_launch(void* const* d_in, const int* in_sizes, int n_in,
                              void* d_out, int out_size, void* d_ws, size_t ws_size,
                              hipStream_t stream) {
    const float* x   = (const float*)d_in[0];
    const float* mf  = (const float*)d_in[1];
    const float* lap = (const float*)d_in[2];
    const int*   ei  = (const int*)d_in[3];
    float* out = (float*)d_out;

    const int  K  = in_sizes[1] - 1;          // 10
    const long NF = (long)in_sizes[0];        // N*F
    const int  N  = (int)(NF / FDIM);         // 100000
    const int  E  = in_sizes[3] / 2;          // 3200000
    const int* row = ei;
    const int* col = ei + E;

    // workspace layout (~170 MB)
    char* wp = (char*)d_ws;
    float*  bufA   = (float*)wp;  wp += NF * sizeof(float);
    float*  bufB   = (float*)wp;  wp += NF * sizeof(float);
    __half* hbufA  = (__half*)wp; wp += NF * sizeof(__half);
    __half* hbufB  = (__half*)wp; wp += NF * sizeof(__half);
    int*    eidx   = (int*)wp;    wp += (size_t)E * sizeof(int);
    int*    rowptr = (int*)wp;    wp += (size_t)(N + 1) * sizeof(int);
    int*    cursor = (int*)wp;    wp += (size_t)N * sizeof(int);
    int*    deg    = (int*)wp;    wp += (size_t)N * sizeof(int);
    float*  dinv   = (float*)wp;  wp += (size_t)N * sizeof(float);
    int*    bsum   = (int*)wp;    wp += 512 * sizeof(int);
    int*    boff   = (int*)wp;    wp += 512 * sizeof(int);

    const int BT = 256;
    const long n8 = NF / 8;
    const int n8_blocks = (int)((n8 + BT - 1) / BT);
    const int n_blocks  = (N + BT - 1) / BT;
    const int M = 192;   // blocks per octant for filtered kernels

    // CSR build
    hipMemsetAsync(deg, 0, (size_t)N * sizeof(int), stream);
    degree_oct_kernel<<<8 * M, BT, 0, stream>>>(col, deg, N, E, M);
    dinv_kernel<<<n_blocks, BT, 0, stream>>>(deg, dinv, N);
    scan_blocks_kernel<<<n_blocks, BT, 0, stream>>>(deg, rowptr, bsum, N);
    scan_bsums_kernel<<<1, 512, 0, stream>>>(bsum, boff, n_blocks);
    add_offsets_kernel<<<n_blocks, BT, 0, stream>>>(rowptr, cursor, boff, N, E);
    place_oct_kernel<<<8 * M, BT, 0, stream>>>(row, col, cursor, eidx, N, E, M);

    // out = mf0 * x ; hbufB = fp16(dinv*x) flat  (hbufB free until i=2 writes it)
    init_out_kernel<<<n8_blocks, BT, 0, stream>>>((const float4*)x, mf, dinv,
                                                  (float4*)out, (float4*)hbufB, n8);

    const int g_blocks = (N + 3) / 4;

    // P1 = prop(x) -> bufA (+hbufA) ; out += c1*P1   (gathers fp16 dinv*x)
    gather_prop_kernel<<<g_blocks, BT, 0, stream>>>(eidx, rowptr, dinv, hbufB, x,
                                                    bufA, hbufA, out, mf, lap,
                                                    1, 1.0f, 0.0f, N);
    // P_i = 2*prop(P_{i-1}) - P_{i-2} ; out += c_i*P_i   (gathers fp16 shadow)
    for (int i = 2; i <= K; ++i) {
        const __half* srch  = (i % 2 == 0) ? hbufA : hbufB;  // fp16(dinv*P_{i-1})
        float*        tgt   = (i % 2 == 0) ? bufB : bufA;    // P_i (overwrites P_{i-2})
        __half*       tgth  = (i % 2 == 0) ? hbufB : hbufA;
        const float*  prev2 = (i == 2) ? x : (const float*)tgt;
        if (i == K) { tgth = nullptr; tgt = nullptr; }  // P_K, shadow_K never read
        gather_prop_kernel<<<g_blocks, BT, 0, stream>>>(eidx, rowptr, dinv, srch, prev2,
                                                        tgt, tgth, out, mf, lap,
                                                        i, 2.0f, -1.0f, N);
    }
}